// Round 14
// baseline (265.132 us; speedup 1.0000x reference)
//
#include <hip/hip_runtime.h>

#define DF 128      // feature dim
#define CHUNK 2048  // edges per chunk in counting sort
#define LSTCAP 6144 // LDS staging cap in p2 (bucket avg ~4096 + slack)

typedef __bf16 bf16x8 __attribute__((ext_vector_type(8)));
typedef float f32x4 __attribute__((ext_vector_type(4)));

// NOTE: packing assumes n <= 65536, NBUCK <= 256, NCHUNK <= 512
// (problem fixes n = 50000, E = 800000 -> NBUCK = 196, NCHUNK = 391).
//
// Algebra: layer1 has no activation, so
//   out = lrelu( S^2 x (W1W2) + rowsum(S) * (b1^T W2) + b2 ),
//   S = D^-1/2 (A+I) D^-1/2,  rowsum(S)[t] = dis[t]*(dis[t] + sum_N dis[s]).
// Pipeline: u = dis*(x@W) [col-blocked bf16]; v = dis^2 * (sum u) [agg1];
//           out = lrelu(dis*(sum v) + r*c1 + b2) [agg2].
// u/v layout: [cb=0..7][node][16 cols] (32 B per node-plane), plane cb pinned
// to XCD cb via blockIdx&7 -> per-XCD gather working set 1.6 MB (L2-resident).

// ---------------------------------------------------------------- utilities
static __device__ __forceinline__ float lrelu(float x) {
  return x > 0.f ? x : 0.1f * x;
}
static __device__ __forceinline__ unsigned short f2bf(float f) {
  unsigned int u = __float_as_uint(f);
  u += 0x7FFFu + ((u >> 16) & 1u);
  return (unsigned short)(u >> 16);
}
static __device__ __forceinline__ float bf2f(unsigned short h) {
  return __uint_as_float((unsigned int)h << 16);
}

// ---------------------------------------------------------------- wprod:
// blocks 0..127: row i of W = W1@W2 (fp32), split hi/lo into MFMA frag order.
// block 128: c1 = b1^T @ W2.
__global__ __launch_bounds__(128) void wprod_kernel(
    const float* __restrict__ W1, const float* __restrict__ W2,
    const float* __restrict__ b1, unsigned short* __restrict__ wfrag,
    float* __restrict__ c1) {
  int j = threadIdx.x;
  if (blockIdx.x < 128) {
    int i = blockIdx.x;
    float acc = 0.f;
    for (int k = 0; k < 128; ++k)
      acc = fmaf(W1[i * 128 + k], W2[k * 128 + j], acc);
    unsigned short h = f2bf(acc);
    unsigned short l = f2bf(acc - bf2f(h));
    int fid = (((i >> 5) * 8) + (j >> 4)) * 64 + ((i >> 3) & 3) * 16 + (j & 15);
    int pos = fid * 8 + (i & 7);
    wfrag[pos] = h;
    wfrag[16384 + pos] = l;
  } else {
    float acc = 0.f;
    for (int k = 0; k < 128; ++k) acc = fmaf(b1[k], W2[k * 128 + j], acc);
    c1[j] = acc;
  }
}

// ---------------------------------------------------------------- pass 1a:
// per-chunk bucket histogram (bucket = target >> 8) + pack pairs.
// int64-vs-int32 detected block-locally (256 odd-word samples).
// M stored TRANSPOSED: M[bucket * NCHUNK + chunk].
__global__ __launch_bounds__(256) void p1a_kernel(
    const void* __restrict__ ei, int E, int* __restrict__ M,
    unsigned int* __restrict__ pairs, int NBUCK, int NCHUNK) {
  __shared__ int h[256];
  __shared__ int any32;
  int tid = threadIdx.x;
  if (tid == 0) any32 = 0;
  h[tid] = 0;
  __syncthreads();
  int base = blockIdx.x * CHUNK;
  int end = min(base + CHUNK, E);
  {
    const unsigned int* u = (const unsigned int*)ei;
    long long i = (long long)base + tid * 8;
    if (i < end && u[2 * i + 1] != 0u) any32 = 1;
  }
  __syncthreads();
  int is64 = !any32;
  if (is64) {
    const long long* p = (const long long*)ei;
    for (int i = base + tid; i < end; i += 256) {
      int src = (int)p[i];
      int c = (int)p[(size_t)E + i];
      atomicAdd(&h[c >> 8], 1);
      pairs[i] = ((unsigned)src << 16) | (unsigned)c;
    }
  } else {
    const int* p = (const int*)ei;
    for (int i = base + tid; i < end; i += 256) {
      int src = p[i];
      int c = p[(size_t)E + i];
      atomicAdd(&h[c >> 8], 1);
      pairs[i] = ((unsigned)src << 16) | (unsigned)c;
    }
  }
  __syncthreads();
  if (tid < NBUCK) M[tid * NCHUNK + blockIdx.x] = h[tid];
}

// ---------------------------------------------------------------- matscanA:
// one block per bucket: exclusive scan of that bucket's chunk row (2/thread).
__global__ __launch_bounds__(256) void matscanA_kernel(int* __restrict__ M,
                                                       int* __restrict__ btot,
                                                       int NCHUNK) {
  __shared__ int s[256];
  int tid = threadIdx.x;
  int base = blockIdx.x * NCHUNK;
  int i0 = tid * 2, i1 = tid * 2 + 1;
  int v0 = (i0 < NCHUNK) ? M[base + i0] : 0;
  int v1 = (i1 < NCHUNK) ? M[base + i1] : 0;
  int loc = v0 + v1;
  s[tid] = loc;
  __syncthreads();
  for (int d = 1; d < 256; d <<= 1) {
    int add = (tid >= d) ? s[tid - d] : 0;
    __syncthreads();
    s[tid] += add;
    __syncthreads();
  }
  int excl = s[tid] - loc;
  if (i0 < NCHUNK) M[base + i0] = excl;
  if (i1 < NCHUNK) M[base + i1] = excl + v0;
  if (tid == 255) btot[blockIdx.x] = s[255];
}

// ---------------------------------------------------------------- pass 1c:
// scatter pairs into exact per-(chunk,bucket) staging slots.
__global__ __launch_bounds__(256) void p1c_kernel(
    const unsigned int* __restrict__ pairs, int E, const int* __restrict__ M,
    const int* __restrict__ btot, int NBUCK, int NCHUNK,
    unsigned int* __restrict__ staging) {
  __shared__ int bs[256];
  __shared__ int rowM[256];
  __shared__ int lcur[256];
  int tid = threadIdx.x;
  int blk = blockIdx.x;
  int v = (tid < NBUCK) ? btot[tid] : 0;
  bs[tid] = v;
  __syncthreads();
  for (int d = 1; d < 256; d <<= 1) {
    int add = (tid >= d) ? bs[tid - d] : 0;
    __syncthreads();
    bs[tid] += add;
    __syncthreads();
  }
  if (tid < NBUCK) rowM[tid] = M[tid * NCHUNK + blk] + (bs[tid] - v);
  lcur[tid] = 0;
  __syncthreads();
  int base = blk * CHUNK;
  int end = min(base + CHUNK, E);
  for (int i = base + tid; i < end; i += 256) {
    unsigned pv = pairs[i];
    int b = (int)((pv & 0xFFFFu) >> 8);
    int r = atomicAdd(&lcur[b], 1);
    staging[rowM[b] + r] = pv;
  }
}

// ---------------------------------------------------------------- pass 2:
// one block per bucket: emit offcnt/dis densely, scatter srcs (ushort).
__global__ __launch_bounds__(256) void p2_kernel(
    const unsigned int* __restrict__ staging, const int* __restrict__ btot,
    int NBUCK, int2* __restrict__ offcnt, float* __restrict__ dis,
    unsigned short* __restrict__ srcs, int n) {
  __shared__ int bs[256], h[256], ex[256], lcur[256];
  __shared__ unsigned int lst[LSTCAP];
  int tid = threadIdx.x;
  int b = blockIdx.x;
  int v = (tid < NBUCK) ? btot[tid] : 0;
  bs[tid] = v;
  h[tid] = 0;
  lcur[tid] = 0;
  __syncthreads();
  for (int d = 1; d < 256; d <<= 1) {
    int add = (tid >= d) ? bs[tid - d] : 0;
    __syncthreads();
    bs[tid] += add;
    __syncthreads();
  }
  int lenb = btot[b];
  int base = bs[b] - lenb;  // exclusive prefix at b
  __syncthreads();
  for (int i = tid; i < lenb; i += 256) {
    unsigned int pv = staging[base + i];
    if (i < LSTCAP) lst[i] = pv;
    atomicAdd(&h[pv & 255u], 1);
  }
  __syncthreads();
  int my = h[tid];
  ex[tid] = my;
  __syncthreads();
  for (int d = 1; d < 256; d <<= 1) {
    int add = (tid >= d) ? ex[tid - d] : 0;
    __syncthreads();
    ex[tid] += add;
    __syncthreads();
  }
  int excl = ex[tid] - my;
  ex[tid] = excl;
  int node = (b << 8) + tid;
  if (node < n) {
    offcnt[node] = make_int2(base + excl, my);
    dis[node] = rsqrtf((float)(my + 1));  // deg incl self loop >= 1
  }
  __syncthreads();
  for (int i = tid; i < lenb; i += 256) {
    unsigned int pv = (i < LSTCAP) ? lst[i] : staging[base + i];
    int ci = (int)(pv & 255u);
    int r = atomicAdd(&lcur[ci], 1);
    srcs[base + ex[ci] + r] = (unsigned short)(pv >> 16);
  }
}

// ---------------------------------------------------------------- rsum:
// r[t] = dis[t] * (dis[t] + sum_{s in N(t)} dis[s])  (dis table L2-resident)
__global__ __launch_bounds__(256) void rsum_kernel(
    const int2* __restrict__ offcnt, const float* __restrict__ dis,
    const unsigned short* __restrict__ srcs, float* __restrict__ r, int n) {
  int t = blockIdx.x * 256 + threadIdx.x;
  if (t >= n) return;
  int2 oc = offcnt[t];
  float dt = dis[t];
  float acc = dt;  // self
  for (int i = 0; i < oc.y; ++i) acc += dis[(int)srcs[oc.x + i]];
  r[t] = dt * acc;
}

// ---------------------------------------------------------------- MFMA GEMM (split bf16 hi/lo, 3 MFMA)
// u[cb][row][16] = bf16( dis[row] * (x @ W)[row][cb*16..] )  (col-blocked)
__global__ __launch_bounds__(256, 8) void gemm_f32_kernel(
    const float* __restrict__ A, const unsigned short* __restrict__ wfrag,
    const float* __restrict__ dis, unsigned short* __restrict__ U, int n) {
  __shared__ unsigned short Ah[2][4][64][8];
  __shared__ unsigned short Al[2][4][64][8];
  __shared__ unsigned short Cs[32 * 136];
  __shared__ float disS[32];
  int tid = threadIdx.x;
  int row0 = blockIdx.x * 32;

  if (tid < 32) {
    int gr = row0 + tid;
    disS[tid] = (gr < n) ? dis[gr] : 0.f;
  }

  const float4* A4 = (const float4*)A;
#pragma unroll
  for (int it = 0; it < 4; ++it) {
    int fi = it * 256 + tid;
    int row = fi >> 5;          // 0..31
    int c4 = fi & 31;           // float4 index along k
    int gr = row0 + row;
    float4 v = make_float4(0.f, 0.f, 0.f, 0.f);
    if (gr < n) v = A4[(size_t)gr * 32 + c4];
    unsigned short h0 = f2bf(v.x), h1 = f2bf(v.y), h2 = f2bf(v.z), h3 = f2bf(v.w);
    unsigned short l0 = f2bf(v.x - bf2f(h0)), l1 = f2bf(v.y - bf2f(h1));
    unsigned short l2 = f2bf(v.z - bf2f(h2)), l3 = f2bf(v.w - bf2f(h3));
    int band = row >> 4;
    int kslab = c4 >> 3;
    int lane = ((c4 >> 1) & 3) * 16 + (row & 15);
    int e0 = (c4 & 1) * 4;
    *(uint2*)&Ah[band][kslab][lane][e0] =
        make_uint2((unsigned int)h0 | ((unsigned int)h1 << 16),
                   (unsigned int)h2 | ((unsigned int)h3 << 16));
    *(uint2*)&Al[band][kslab][lane][e0] =
        make_uint2((unsigned int)l0 | ((unsigned int)l1 << 16),
                   (unsigned int)l2 | ((unsigned int)l3 << 16));
  }
  __syncthreads();

  int w = tid >> 6, lane = tid & 63;
  int band = w & 1, ch = w >> 1;

  f32x4 acc[4];
#pragma unroll
  for (int t = 0; t < 4; ++t) acc[t] = (f32x4){0.f, 0.f, 0.f, 0.f};

#pragma unroll
  for (int ks = 0; ks < 4; ++ks) {
    bf16x8 ahi = *(const bf16x8*)&Ah[band][ks][lane][0];
    bf16x8 alo = *(const bf16x8*)&Al[band][ks][lane][0];
#pragma unroll
    for (int ct = 0; ct < 4; ++ct) {
      size_t fb = ((size_t)(ks * 8 + ch * 4 + ct) * 64 + lane) * 8;
      bf16x8 whi = *(const bf16x8*)&wfrag[fb];
      bf16x8 wlo = *(const bf16x8*)&wfrag[16384 + fb];
      acc[ct] = __builtin_amdgcn_mfma_f32_16x16x32_bf16(ahi, whi, acc[ct], 0, 0, 0);
      acc[ct] = __builtin_amdgcn_mfma_f32_16x16x32_bf16(ahi, wlo, acc[ct], 0, 0, 0);
      acc[ct] = __builtin_amdgcn_mfma_f32_16x16x32_bf16(alo, whi, acc[ct], 0, 0, 0);
    }
  }

#pragma unroll
  for (int ct = 0; ct < 4; ++ct) {
    int col = ch * 64 + ct * 16 + (lane & 15);
#pragma unroll
    for (int r = 0; r < 4; ++r) {
      int lrow = band * 16 + ((lane >> 4) << 2) + r;
      Cs[lrow * 136 + col] = f2bf(acc[ct][r] * disS[lrow]);
    }
  }
  __syncthreads();
  // store col-blocked: wave -> one cb plane, 32 rows x 32 B contiguous
#pragma unroll
  for (int it = 0; it < 2; ++it) {
    int fi = it * 256 + tid;    // 0..511
    int cb = fi >> 6;           // 0..7
    int rr = (fi & 63) >> 1;    // 0..31
    int half = fi & 1;          // 0..1
    int gr = row0 + rr;
    if (gr < n)
      *(uint4*)(U + ((size_t)cb * n + gr) * 16 + half * 8) =
          *(uint4*)&Cs[rr * 136 + cb * 16 + half * 8];
  }
}

// ---------------------------------------------------------------- aggregation (col-blocked, XCD-affine)
// block handles plane cb = blockIdx&7 for groups of 8 nodes (wave per node).
// wave: 16 edge-slots x 4 lanes x uint2 (4 bf16 cols); shfl-reduce 4 levels.
// OUT==0: v[t] = bf16(dis^2 * (sum u))        (no bias)
// OUT==1: out[t] = lrelu(dis*(sum v) + r*c1 + b2)  (f32 row-major)
template <int OUT>
__global__ __launch_bounds__(512) void aggcb_kernel(
    const unsigned short* __restrict__ u, const unsigned short* __restrict__ srcs,
    const int2* __restrict__ offcnt, const float* __restrict__ dis,
    const float* __restrict__ r, const float* __restrict__ c1,
    const float* __restrict__ b2, void* __restrict__ outv, int n, int ngrp) {
  int cb = blockIdx.x & 7;
  int wv = threadIdx.x >> 6;
  int lane = threadIdx.x & 63;
  int slot = lane >> 2;   // 0..15
  int cq = lane & 3;      // uint2 idx: cols 4cq..4cq+3 of this 16-col plane
  const unsigned short* up = u + (size_t)cb * n * 16;
  int ngrid = gridDim.x >> 3;

  for (int grp = blockIdx.x >> 3; grp < ngrp; grp += ngrid) {
    int wid = grp * 8 + wv;
    if (wid >= n) continue;

    float a0 = 0.f, a1 = 0.f, a2 = 0.f, a3 = 0.f;
#define ACC_U2(U)                                \
    do {                                         \
      a0 += __uint_as_float((U).x << 16);        \
      a1 += __uint_as_float((U).x & 0xFFFF0000u);\
      a2 += __uint_as_float((U).y << 16);        \
      a3 += __uint_as_float((U).y & 0xFFFF0000u);\
    } while (0)

    if (slot == 0) {  // self term
      uint2 sv = ((const uint2*)(up + (size_t)wid * 16))[cq];
      ACC_U2(sv);
    }
    int2 oc = offcnt[wid];
    int s = oc.x, e = s + oc.y, jb = s;
    for (; jb + 16 <= e; jb += 16) {
      int s0 = (int)srcs[jb + slot];
      uint2 u0 = ((const uint2*)(up + (size_t)s0 * 16))[cq];
      ACC_U2(u0);
    }
    int rem = e - jb;  // 0..15
    if (slot < rem) {
      int s0 = (int)srcs[jb + slot];
      uint2 u0 = ((const uint2*)(up + (size_t)s0 * 16))[cq];
      ACC_U2(u0);
    }
#undef ACC_U2

    // reduce over 16 slots (lanes differing in bits 2..5)
    a0 += __shfl_xor(a0, 4, 64);  a1 += __shfl_xor(a1, 4, 64);
    a2 += __shfl_xor(a2, 4, 64);  a3 += __shfl_xor(a3, 4, 64);
    a0 += __shfl_xor(a0, 8, 64);  a1 += __shfl_xor(a1, 8, 64);
    a2 += __shfl_xor(a2, 8, 64);  a3 += __shfl_xor(a3, 8, 64);
    a0 += __shfl_xor(a0, 16, 64); a1 += __shfl_xor(a1, 16, 64);
    a2 += __shfl_xor(a2, 16, 64); a3 += __shfl_xor(a3, 16, 64);
    a0 += __shfl_xor(a0, 32, 64); a1 += __shfl_xor(a1, 32, 64);
    a2 += __shfl_xor(a2, 32, 64); a3 += __shfl_xor(a3, 32, 64);

    if (slot == 0) {
      float dw = dis[wid];
      if (OUT == 0) {
        float sc = dw * dw;
        uint2 p;
        p.x = (unsigned)f2bf(a0 * sc) | ((unsigned)f2bf(a1 * sc) << 16);
        p.y = (unsigned)f2bf(a2 * sc) | ((unsigned)f2bf(a3 * sc) << 16);
        ((uint2*)((unsigned short*)outv + ((size_t)cb * n + wid) * 16))[cq] = p;
      } else {
        float rv = r[wid];
        float4 cc = *(const float4*)&c1[cb * 16 + cq * 4];
        float4 bb = *(const float4*)&b2[cb * 16 + cq * 4];
        float4 o;
        o.x = lrelu(fmaf(a0, dw, fmaf(rv, cc.x, bb.x)));
        o.y = lrelu(fmaf(a1, dw, fmaf(rv, cc.y, bb.y)));
        o.z = lrelu(fmaf(a2, dw, fmaf(rv, cc.z, bb.z)));
        o.w = lrelu(fmaf(a3, dw, fmaf(rv, cc.w, bb.w)));
        *(float4*)((float*)outv + (size_t)wid * DF + cb * 16 + cq * 4) = o;
      }
    }
  }
}

// ---------------------------------------------------------------- launch
extern "C" void kernel_launch(void* const* d_in, const int* in_sizes, int n_in,
                              void* d_out, int out_size, void* d_ws, size_t ws_size,
                              hipStream_t stream) {
  const float* x  = (const float*)d_in[0];
  const void*  ei = d_in[1];
  const float* W1 = (const float*)d_in[2];
  const float* b1 = (const float*)d_in[3];
  const float* W2 = (const float*)d_in[4];
  const float* b2 = (const float*)d_in[5];
  float* out = (float*)d_out;

  int n = in_sizes[0] / DF;  // 50000
  int E = in_sizes[1] / 2;   // 800000
  int NBUCK = (n + 255) >> 8;              // 196
  int NCHUNK = (E + CHUNK - 1) / CHUNK;    // 391

  // workspace carve (16B aligned)
  char* w = (char*)d_ws;
  auto carve = [&](size_t bytes) {
    char* p = w;
    w += (bytes + 15) & ~(size_t)15;
    return p;
  };
  float* dis    = (float*)carve((size_t)n * 4);
  float* rарr   = nullptr;  // placeholder to keep alignment readable
  float* rr     = (float*)carve((size_t)n * 4);
  int2*  offcnt = (int2*)carve((size_t)n * 8);
  int*   btot   = (int*)carve((size_t)NBUCK * 4);
  int*   M      = (int*)carve((size_t)NBUCK * NCHUNK * 4);
  unsigned short* wfrag = (unsigned short*)carve(65536);   // hi+lo of W1W2
  float* c1     = (float*)carve(512);
  unsigned int* pairs   = (unsigned int*)carve((size_t)E * 4);
  unsigned int* staging = (unsigned int*)carve((size_t)E * 4);
  unsigned short* srcs  = (unsigned short*)carve((size_t)E * 2);
  unsigned short* bufU  = (unsigned short*)carve((size_t)8 * n * 16 * 2);
  unsigned short* bufV  = (unsigned short*)carve((size_t)8 * n * 16 * 2);
  (void)rарr;

  // W = W1@W2 (fp32) -> frag hi/lo; c1 = b1^T W2
  wprod_kernel<<<129, 128, 0, stream>>>(W1, W2, b1, wfrag, c1);
  // CSR build: exact counting sort by bucket = target>>8 (no global atomics)
  p1a_kernel<<<NCHUNK, 256, 0, stream>>>(ei, E, M, pairs, NBUCK, NCHUNK);
  matscanA_kernel<<<NBUCK, 256, 0, stream>>>(M, btot, NCHUNK);
  p1c_kernel<<<NCHUNK, 256, 0, stream>>>(pairs, E, M, btot, NBUCK, NCHUNK,
                                         staging);
  p2_kernel<<<NBUCK, 256, 0, stream>>>(staging, btot, NBUCK, offcnt, dis,
                                       srcs, n);
  rsum_kernel<<<(n + 255) / 256, 256, 0, stream>>>(offcnt, dis, srcs, rr, n);

  int gGemm = (n + 31) / 32;       // 1563
  int ngrp  = (n + 7) / 8;         // 6250
  int gAgg  = 2048;                // 256 group-strides x 8 cb planes

  // u = dis * (x @ W), col-blocked bf16
  gemm_f32_kernel<<<gGemm, 256, 0, stream>>>(x, wfrag, dis, bufU, n);
  // v = dis^2 * (sum_N+ u), col-blocked bf16
  aggcb_kernel<0><<<gAgg, 512, 0, stream>>>(bufU, srcs, offcnt, dis, rr, c1,
                                            b2, bufV, n, ngrp);
  // out = lrelu(dis * (sum_N+ v) + r*c1 + b2), f32 row-major
  aggcb_kernel<1><<<gAgg, 512, 0, stream>>>(bufV, srcs, offcnt, dis, rr, c1,
                                            b2, out, n, ngrp);
}

// Round 15
// 131.611 us; speedup vs baseline: 2.0145x; 2.0145x over previous
//
#include <hip/hip_runtime.h>

#define DF 128      // feature dim
#define CHUNK 2048  // edges per chunk in counting sort
#define LSTCAP 6144 // LDS staging cap in p2 (bucket avg ~4096 + slack)

typedef __bf16 bf16x8 __attribute__((ext_vector_type(8)));
typedef float f32x4 __attribute__((ext_vector_type(4)));

// NOTE: packing assumes n <= 65536, NBUCK <= 256, NCHUNK <= 512.
//
// Algebra (layer1 has no activation):
//   out = lrelu( S^2 x (W1W2) + rowsum(S) * (b1^T W2) + b2 ),
//   S = D^-1/2 (A+I) D^-1/2,  rowsum(S)[t] = dis[t]*(dis[t] + sum_N dis[s]).
// Pipeline: u = dis*(x@W) bf16 row-major; v = bf16(dis^2 * (sum u));
//           out = lrelu(dis*(sum v) + r*c1 + b2).

// ---------------------------------------------------------------- utilities
static __device__ __forceinline__ float lrelu(float x) {
  return x > 0.f ? x : 0.1f * x;
}
static __device__ __forceinline__ unsigned short f2bf(float f) {
  unsigned int u = __float_as_uint(f);
  u += 0x7FFFu + ((u >> 16) & 1u);
  return (unsigned short)(u >> 16);
}
static __device__ __forceinline__ float bf2f(unsigned short h) {
  return __uint_as_float((unsigned int)h << 16);
}

// ---------------------------------------------------------------- wprod:
// blocks 0..127: row i of W = W1@W2 (fp32), split hi/lo into MFMA frag order.
// block 128: c1 = b1^T @ W2.
__global__ __launch_bounds__(128) void wprod_kernel(
    const float* __restrict__ W1, const float* __restrict__ W2,
    const float* __restrict__ b1, unsigned short* __restrict__ wfrag,
    float* __restrict__ c1) {
  int j = threadIdx.x;
  if (blockIdx.x < 128) {
    int i = blockIdx.x;
    float acc = 0.f;
    for (int k = 0; k < 128; ++k)
      acc = fmaf(W1[i * 128 + k], W2[k * 128 + j], acc);
    unsigned short h = f2bf(acc);
    unsigned short l = f2bf(acc - bf2f(h));
    int fid = (((i >> 5) * 8) + (j >> 4)) * 64 + ((i >> 3) & 3) * 16 + (j & 15);
    int pos = fid * 8 + (i & 7);
    wfrag[pos] = h;
    wfrag[16384 + pos] = l;
  } else {
    float acc = 0.f;
    for (int k = 0; k < 128; ++k) acc = fmaf(b1[k], W2[k * 128 + j], acc);
    c1[j] = acc;
  }
}

// ---------------------------------------------------------------- pass 1a:
// per-chunk bucket histogram (bucket = target >> 8) + pack pairs.
// int64-vs-int32 detected block-locally (256 odd-word samples).
// M stored TRANSPOSED: M[bucket * NCHUNK + chunk].
__global__ __launch_bounds__(256) void p1a_kernel(
    const void* __restrict__ ei, int E, int* __restrict__ M,
    unsigned int* __restrict__ pairs, int NBUCK, int NCHUNK) {
  __shared__ int h[256];
  __shared__ int any32;
  int tid = threadIdx.x;
  if (tid == 0) any32 = 0;
  h[tid] = 0;
  __syncthreads();
  int base = blockIdx.x * CHUNK;
  int end = min(base + CHUNK, E);
  {
    const unsigned int* u = (const unsigned int*)ei;
    long long i = (long long)base + tid * 8;
    if (i < end && u[2 * i + 1] != 0u) any32 = 1;
  }
  __syncthreads();
  int is64 = !any32;
  if (is64) {
    const long long* p = (const long long*)ei;
    for (int i = base + tid; i < end; i += 256) {
      int src = (int)p[i];
      int c = (int)p[(size_t)E + i];
      atomicAdd(&h[c >> 8], 1);
      pairs[i] = ((unsigned)src << 16) | (unsigned)c;
    }
  } else {
    const int* p = (const int*)ei;
    for (int i = base + tid; i < end; i += 256) {
      int src = p[i];
      int c = p[(size_t)E + i];
      atomicAdd(&h[c >> 8], 1);
      pairs[i] = ((unsigned)src << 16) | (unsigned)c;
    }
  }
  __syncthreads();
  if (tid < NBUCK) M[tid * NCHUNK + blockIdx.x] = h[tid];
}

// ---------------------------------------------------------------- matscanA:
// one block per bucket: exclusive scan of that bucket's chunk row (2/thread).
__global__ __launch_bounds__(256) void matscanA_kernel(int* __restrict__ M,
                                                       int* __restrict__ btot,
                                                       int NCHUNK) {
  __shared__ int s[256];
  int tid = threadIdx.x;
  int base = blockIdx.x * NCHUNK;
  int i0 = tid * 2, i1 = tid * 2 + 1;
  int v0 = (i0 < NCHUNK) ? M[base + i0] : 0;
  int v1 = (i1 < NCHUNK) ? M[base + i1] : 0;
  int loc = v0 + v1;
  s[tid] = loc;
  __syncthreads();
  for (int d = 1; d < 256; d <<= 1) {
    int add = (tid >= d) ? s[tid - d] : 0;
    __syncthreads();
    s[tid] += add;
    __syncthreads();
  }
  int excl = s[tid] - loc;
  if (i0 < NCHUNK) M[base + i0] = excl;
  if (i1 < NCHUNK) M[base + i1] = excl + v0;
  if (tid == 255) btot[blockIdx.x] = s[255];
}

// ---------------------------------------------------------------- pass 1c:
// scatter pairs into exact per-(chunk,bucket) staging slots.
__global__ __launch_bounds__(256) void p1c_kernel(
    const unsigned int* __restrict__ pairs, int E, const int* __restrict__ M,
    const int* __restrict__ btot, int NBUCK, int NCHUNK,
    unsigned int* __restrict__ staging) {
  __shared__ int bs[256];
  __shared__ int rowM[256];
  __shared__ int lcur[256];
  int tid = threadIdx.x;
  int blk = blockIdx.x;
  int v = (tid < NBUCK) ? btot[tid] : 0;
  bs[tid] = v;
  __syncthreads();
  for (int d = 1; d < 256; d <<= 1) {
    int add = (tid >= d) ? bs[tid - d] : 0;
    __syncthreads();
    bs[tid] += add;
    __syncthreads();
  }
  if (tid < NBUCK) rowM[tid] = M[tid * NCHUNK + blk] + (bs[tid] - v);
  lcur[tid] = 0;
  __syncthreads();
  int base = blk * CHUNK;
  int end = min(base + CHUNK, E);
  for (int i = base + tid; i < end; i += 256) {
    unsigned pv = pairs[i];
    int b = (int)((pv & 0xFFFFu) >> 8);
    int r = atomicAdd(&lcur[b], 1);
    staging[rowM[b] + r] = pv;
  }
}

// ---------------------------------------------------------------- pass 2:
// one block per bucket: emit offcnt/dis densely, scatter srcs (ushort).
__global__ __launch_bounds__(256) void p2_kernel(
    const unsigned int* __restrict__ staging, const int* __restrict__ btot,
    int NBUCK, int2* __restrict__ offcnt, float* __restrict__ dis,
    unsigned short* __restrict__ srcs, int n) {
  __shared__ int bs[256], h[256], ex[256], lcur[256];
  __shared__ unsigned int lst[LSTCAP];
  int tid = threadIdx.x;
  int b = blockIdx.x;
  int v = (tid < NBUCK) ? btot[tid] : 0;
  bs[tid] = v;
  h[tid] = 0;
  lcur[tid] = 0;
  __syncthreads();
  for (int d = 1; d < 256; d <<= 1) {
    int add = (tid >= d) ? bs[tid - d] : 0;
    __syncthreads();
    bs[tid] += add;
    __syncthreads();
  }
  int lenb = btot[b];
  int base = bs[b] - lenb;  // exclusive prefix at b
  __syncthreads();
  for (int i = tid; i < lenb; i += 256) {
    unsigned int pv = staging[base + i];
    if (i < LSTCAP) lst[i] = pv;
    atomicAdd(&h[pv & 255u], 1);
  }
  __syncthreads();
  int my = h[tid];
  ex[tid] = my;
  __syncthreads();
  for (int d = 1; d < 256; d <<= 1) {
    int add = (tid >= d) ? ex[tid - d] : 0;
    __syncthreads();
    ex[tid] += add;
    __syncthreads();
  }
  int excl = ex[tid] - my;
  ex[tid] = excl;
  int node = (b << 8) + tid;
  if (node < n) {
    offcnt[node] = make_int2(base + excl, my);
    dis[node] = rsqrtf((float)(my + 1));  // deg incl self loop >= 1
  }
  __syncthreads();
  for (int i = tid; i < lenb; i += 256) {
    unsigned int pv = (i < LSTCAP) ? lst[i] : staging[base + i];
    int ci = (int)(pv & 255u);
    int r = atomicAdd(&lcur[ci], 1);
    srcs[base + ex[ci] + r] = (unsigned short)(pv >> 16);
  }
}

// ---------------------------------------------------------------- rsum:
// r[t] = dis[t] * (dis[t] + sum_{s in N(t)} dis[s])  (dis table L2-resident)
__global__ __launch_bounds__(256) void rsum_kernel(
    const int2* __restrict__ offcnt, const float* __restrict__ dis,
    const unsigned short* __restrict__ srcs, float* __restrict__ r, int n) {
  int t = blockIdx.x * 256 + threadIdx.x;
  if (t >= n) return;
  int2 oc = offcnt[t];
  float dt = dis[t];
  float acc = dt;  // self
  for (int i = 0; i < oc.y; ++i) acc += dis[(int)srcs[oc.x + i]];
  r[t] = dt * acc;
}

// ---------------------------------------------------------------- MFMA GEMM (split bf16 hi/lo, 3 MFMA)
// U_bf16[n x 128] = dis[row] * (A_f32[n x 128] @ W[128 x 128]), row-major.
// Epilogue: stage C tile in LDS (stride 136), store coalesced uint4.
__global__ __launch_bounds__(256, 8) void gemm_f32_kernel(
    const float* __restrict__ A, const unsigned short* __restrict__ wfrag,
    const float* __restrict__ dis, unsigned short* __restrict__ G, int n) {
  __shared__ unsigned short Ah[2][4][64][8];
  __shared__ unsigned short Al[2][4][64][8];
  __shared__ unsigned short Cs[32 * 136];
  __shared__ float disS[32];
  int tid = threadIdx.x;
  int row0 = blockIdx.x * 32;

  if (tid < 32) {
    int gr = row0 + tid;
    disS[tid] = (gr < n) ? dis[gr] : 0.f;
  }

  const float4* A4 = (const float4*)A;
#pragma unroll
  for (int it = 0; it < 4; ++it) {
    int fi = it * 256 + tid;
    int row = fi >> 5;          // 0..31
    int c4 = fi & 31;           // float4 index along k
    int gr = row0 + row;
    float4 v = make_float4(0.f, 0.f, 0.f, 0.f);
    if (gr < n) v = A4[(size_t)gr * 32 + c4];
    unsigned short h0 = f2bf(v.x), h1 = f2bf(v.y), h2 = f2bf(v.z), h3 = f2bf(v.w);
    unsigned short l0 = f2bf(v.x - bf2f(h0)), l1 = f2bf(v.y - bf2f(h1));
    unsigned short l2 = f2bf(v.z - bf2f(h2)), l3 = f2bf(v.w - bf2f(h3));
    int band = row >> 4;
    int kslab = c4 >> 3;
    int lane = ((c4 >> 1) & 3) * 16 + (row & 15);
    int e0 = (c4 & 1) * 4;
    *(uint2*)&Ah[band][kslab][lane][e0] =
        make_uint2((unsigned int)h0 | ((unsigned int)h1 << 16),
                   (unsigned int)h2 | ((unsigned int)h3 << 16));
    *(uint2*)&Al[band][kslab][lane][e0] =
        make_uint2((unsigned int)l0 | ((unsigned int)l1 << 16),
                   (unsigned int)l2 | ((unsigned int)l3 << 16));
  }
  __syncthreads();

  int w = tid >> 6, lane = tid & 63;
  int band = w & 1, ch = w >> 1;

  f32x4 acc[4];
#pragma unroll
  for (int t = 0; t < 4; ++t) acc[t] = (f32x4){0.f, 0.f, 0.f, 0.f};

#pragma unroll
  for (int ks = 0; ks < 4; ++ks) {
    bf16x8 ahi = *(const bf16x8*)&Ah[band][ks][lane][0];
    bf16x8 alo = *(const bf16x8*)&Al[band][ks][lane][0];
#pragma unroll
    for (int ct = 0; ct < 4; ++ct) {
      size_t fb = ((size_t)(ks * 8 + ch * 4 + ct) * 64 + lane) * 8;
      bf16x8 whi = *(const bf16x8*)&wfrag[fb];
      bf16x8 wlo = *(const bf16x8*)&wfrag[16384 + fb];
      acc[ct] = __builtin_amdgcn_mfma_f32_16x16x32_bf16(ahi, whi, acc[ct], 0, 0, 0);
      acc[ct] = __builtin_amdgcn_mfma_f32_16x16x32_bf16(ahi, wlo, acc[ct], 0, 0, 0);
      acc[ct] = __builtin_amdgcn_mfma_f32_16x16x32_bf16(alo, whi, acc[ct], 0, 0, 0);
    }
  }

#pragma unroll
  for (int ct = 0; ct < 4; ++ct) {
    int col = ch * 64 + ct * 16 + (lane & 15);
#pragma unroll
    for (int r = 0; r < 4; ++r) {
      int lrow = band * 16 + ((lane >> 4) << 2) + r;
      Cs[lrow * 136 + col] = f2bf(acc[ct][r] * disS[lrow]);
    }
  }
  __syncthreads();
#pragma unroll
  for (int it = 0; it < 2; ++it) {
    int fi = it * 256 + tid;   // 0..511 = 32 rows x 16 uint4
    int row = fi >> 4, q = fi & 15;
    int gr = row0 + row;
    if (gr < n)
      ((uint4*)(G + (size_t)gr * DF))[q] = *(uint4*)&Cs[row * 136 + q * 8];
  }
}

// ---------------------------------------------------------------- aggregation
// wave per node; 4 edge-slots x 16 lanes; each lane gathers uint4 (8 bf16
// cols). Unroll 4 -> 16 edge-gathers in flight. Combine via shfl_xor(16,32).
// acc = sum_{s in N(t)} g[s] + g[t]
// OUT==0: v = bf16(dis^2 * acc)                       (bf16 row-major)
// OUT==1: out = lrelu(dis*acc + r*c1 + b2)            (f32 row-major)
template <int OUT>
__global__ __launch_bounds__(512) void agg_kernel(
    const unsigned short* __restrict__ g, const unsigned short* __restrict__ srcs,
    const int2* __restrict__ offcnt, const float* __restrict__ dis,
    const float* __restrict__ r, const float* __restrict__ c1,
    const float* __restrict__ b2, void* __restrict__ outv, int n) {
  int wid = (blockIdx.x * blockDim.x + threadIdx.x) >> 6;
  int lane = threadIdx.x & 63;
  if (wid >= n) return;
  int slot = lane >> 4;   // 0..3
  int cp = lane & 15;     // uint4 index: cols 8cp..8cp+7

  float a0 = 0.f, a1 = 0.f, a2 = 0.f, a3 = 0.f;
  float a4 = 0.f, a5 = 0.f, a6 = 0.f, a7 = 0.f;

#define ACC_U4(U)                                \
  do {                                           \
    a0 += __uint_as_float((U).x << 16);          \
    a1 += __uint_as_float((U).x & 0xFFFF0000u);  \
    a2 += __uint_as_float((U).y << 16);          \
    a3 += __uint_as_float((U).y & 0xFFFF0000u);  \
    a4 += __uint_as_float((U).z << 16);          \
    a5 += __uint_as_float((U).z & 0xFFFF0000u);  \
    a6 += __uint_as_float((U).w << 16);          \
    a7 += __uint_as_float((U).w & 0xFFFF0000u);  \
  } while (0)

  if (slot == 0) {  // self term g[wid] (added once)
    uint4 sv = ((const uint4*)(g + (size_t)wid * DF))[cp];
    ACC_U4(sv);
  }

  int2 oc = offcnt[wid];
  int s = oc.x;
  int e = s + oc.y;
  int jb = s;
  int m16 = s + (((e - s) >> 4) << 4);
  for (; jb < m16; jb += 16) {  // 4 loads in flight x 4 slots
    int s0 = (int)srcs[jb + slot];
    int s1 = (int)srcs[jb + 4 + slot];
    int s2 = (int)srcs[jb + 8 + slot];
    int s3 = (int)srcs[jb + 12 + slot];
    uint4 u0 = ((const uint4*)(g + (size_t)s0 * DF))[cp];
    uint4 u1 = ((const uint4*)(g + (size_t)s1 * DF))[cp];
    uint4 u2 = ((const uint4*)(g + (size_t)s2 * DF))[cp];
    uint4 u3 = ((const uint4*)(g + (size_t)s3 * DF))[cp];
    ACC_U4(u0);
    ACC_U4(u1);
    ACC_U4(u2);
    ACC_U4(u3);
  }
  if (jb + 8 <= e) {  // 2 x 4 slots
    int s0 = (int)srcs[jb + slot];
    int s1 = (int)srcs[jb + 4 + slot];
    uint4 u0 = ((const uint4*)(g + (size_t)s0 * DF))[cp];
    uint4 u1 = ((const uint4*)(g + (size_t)s1 * DF))[cp];
    ACC_U4(u0);
    ACC_U4(u1);
    jb += 8;
  }
  if (jb + 4 <= e) {  // 1 x 4 slots
    int s0 = (int)srcs[jb + slot];
    uint4 u0 = ((const uint4*)(g + (size_t)s0 * DF))[cp];
    ACC_U4(u0);
    jb += 4;
  }
  int rem = e - jb;  // 0..3
  if (slot < rem) {
    int s0 = (int)srcs[jb + slot];
    uint4 u0 = ((const uint4*)(g + (size_t)s0 * DF))[cp];
    ACC_U4(u0);
  }
#undef ACC_U4

  // combine the four slots (lanes L, L^16, L^32, L^48 hold same cols)
  a0 += __shfl_xor(a0, 16, 64); a1 += __shfl_xor(a1, 16, 64);
  a2 += __shfl_xor(a2, 16, 64); a3 += __shfl_xor(a3, 16, 64);
  a4 += __shfl_xor(a4, 16, 64); a5 += __shfl_xor(a5, 16, 64);
  a6 += __shfl_xor(a6, 16, 64); a7 += __shfl_xor(a7, 16, 64);
  a0 += __shfl_xor(a0, 32, 64); a1 += __shfl_xor(a1, 32, 64);
  a2 += __shfl_xor(a2, 32, 64); a3 += __shfl_xor(a3, 32, 64);
  a4 += __shfl_xor(a4, 32, 64); a5 += __shfl_xor(a5, 32, 64);
  a6 += __shfl_xor(a6, 32, 64); a7 += __shfl_xor(a7, 32, 64);

  if (slot == 0) {
    float dw = dis[wid];
    if (OUT == 0) {
      float sc = dw * dw;
      uint4 p;
      p.x = (unsigned int)f2bf(a0 * sc) | ((unsigned int)f2bf(a1 * sc) << 16);
      p.y = (unsigned int)f2bf(a2 * sc) | ((unsigned int)f2bf(a3 * sc) << 16);
      p.z = (unsigned int)f2bf(a4 * sc) | ((unsigned int)f2bf(a5 * sc) << 16);
      p.w = (unsigned int)f2bf(a6 * sc) | ((unsigned int)f2bf(a7 * sc) << 16);
      ((uint4*)((unsigned short*)outv + (size_t)wid * DF))[cp] = p;
    } else {
      float rv = r[wid];
      float4 c0 = *(const float4*)&c1[cp * 8];
      float4 c4v = *(const float4*)&c1[cp * 8 + 4];
      float4 bb0 = *(const float4*)&b2[cp * 8];
      float4 bb4 = *(const float4*)&b2[cp * 8 + 4];
      float4 r0, r1;
      r0.x = lrelu(fmaf(a0, dw, fmaf(rv, c0.x, bb0.x)));
      r0.y = lrelu(fmaf(a1, dw, fmaf(rv, c0.y, bb0.y)));
      r0.z = lrelu(fmaf(a2, dw, fmaf(rv, c0.z, bb0.z)));
      r0.w = lrelu(fmaf(a3, dw, fmaf(rv, c0.w, bb0.w)));
      r1.x = lrelu(fmaf(a4, dw, fmaf(rv, c4v.x, bb4.x)));
      r1.y = lrelu(fmaf(a5, dw, fmaf(rv, c4v.y, bb4.y)));
      r1.z = lrelu(fmaf(a6, dw, fmaf(rv, c4v.z, bb4.z)));
      r1.w = lrelu(fmaf(a7, dw, fmaf(rv, c4v.w, bb4.w)));
      ((float4*)((float*)outv + (size_t)wid * DF))[2 * cp] = r0;
      ((float4*)((float*)outv + (size_t)wid * DF))[2 * cp + 1] = r1;
    }
  }
}

// ---------------------------------------------------------------- launch
extern "C" void kernel_launch(void* const* d_in, const int* in_sizes, int n_in,
                              void* d_out, int out_size, void* d_ws, size_t ws_size,
                              hipStream_t stream) {
  const float* x  = (const float*)d_in[0];
  const void*  ei = d_in[1];
  const float* W1 = (const float*)d_in[2];
  const float* b1 = (const float*)d_in[3];
  const float* W2 = (const float*)d_in[4];
  const float* b2 = (const float*)d_in[5];
  float* out = (float*)d_out;

  int n = in_sizes[0] / DF;  // 50000
  int E = in_sizes[1] / 2;   // 800000
  int NBUCK = (n + 255) >> 8;              // 196
  int NCHUNK = (E + CHUNK - 1) / CHUNK;    // 391

  // workspace carve (16B aligned)
  char* w = (char*)d_ws;
  auto carve = [&](size_t bytes) {
    char* p = w;
    w += (bytes + 15) & ~(size_t)15;
    return p;
  };
  float* dis    = (float*)carve((size_t)n * 4);
  float* rr     = (float*)carve((size_t)n * 4);
  int2*  offcnt = (int2*)carve((size_t)n * 8);
  int*   btot   = (int*)carve((size_t)NBUCK * 4);
  int*   M      = (int*)carve((size_t)NBUCK * NCHUNK * 4);
  unsigned short* wfrag = (unsigned short*)carve(65536);   // hi+lo of W1W2
  float* c1     = (float*)carve(512);
  unsigned int* pairs   = (unsigned int*)carve((size_t)E * 4);
  unsigned int* staging = (unsigned int*)carve((size_t)E * 4);
  unsigned short* srcs  = (unsigned short*)carve((size_t)E * 2);
  unsigned short* bufU  = (unsigned short*)carve((size_t)n * DF * 2);
  unsigned short* bufV  = (unsigned short*)carve((size_t)n * DF * 2);

  // W = W1@W2 (fp32) -> frag hi/lo; c1 = b1^T W2
  wprod_kernel<<<129, 128, 0, stream>>>(W1, W2, b1, wfrag, c1);
  // CSR build: exact counting sort by bucket = target>>8 (no global atomics)
  p1a_kernel<<<NCHUNK, 256, 0, stream>>>(ei, E, M, pairs, NBUCK, NCHUNK);
  matscanA_kernel<<<NBUCK, 256, 0, stream>>>(M, btot, NCHUNK);
  p1c_kernel<<<NCHUNK, 256, 0, stream>>>(pairs, E, M, btot, NBUCK, NCHUNK,
                                         staging);
  p2_kernel<<<NBUCK, 256, 0, stream>>>(staging, btot, NBUCK, offcnt, dis,
                                       srcs, n);
  rsum_kernel<<<(n + 255) / 256, 256, 0, stream>>>(offcnt, dis, srcs, rr, n);

  int gGemm = (n + 31) / 32;        // 1563
  int gAgg  = (n + 7) / 8;          // 6250 (8 waves/block)

  // u = dis * (x @ W), row-major bf16
  gemm_f32_kernel<<<gGemm, 256, 0, stream>>>(x, wfrag, dis, bufU, n);
  // v = bf16(dis^2 * (sum_N+ u))
  agg_kernel<0><<<gAgg, 512, 0, stream>>>(bufU, srcs, offcnt, dis, rr, c1, b2,
                                          bufV, n);
  // out = lrelu(dis * (sum_N+ v) + r*c1 + b2), f32 row-major
  agg_kernel<1><<<gAgg, 512, 0, stream>>>(bufV, srcs, offcnt, dis, rr, c1, b2,
                                          out, n);
}

// Round 16
// 121.429 us; speedup vs baseline: 2.1834x; 1.0838x over previous
//
#include <hip/hip_runtime.h>

#define DF 128      // feature dim
#define CHUNK 2048  // edges per chunk in counting sort
#define LSTCAP 6144 // LDS staging cap in p2 (bucket avg ~4096 + slack)

typedef __bf16 bf16x8 __attribute__((ext_vector_type(8)));
typedef float f32x4 __attribute__((ext_vector_type(4)));

// NOTE: packing assumes n <= 65536, NBUCK <= 256, NCHUNK <= 512.
//
// Algebra (layer1 has no activation):
//   out = lrelu( S^2 x (W1W2) + rowsum(S) * (b1^T W2) + b2 ),
//   S = D^-1/2 (A+I) D^-1/2,  rowsum(S)[t] = dis[t]*(dis[t] + sum_N dis[s]).
// Pipeline: u = dis*(x@W); v = bf16(dis^2 * (sum u)); out = lrelu(dis*(sum v)
//           + r*c1 + b2).
// u/v stored PLANE-BLOCKED: [plane=4][node][32 cols bf16] (64 B/node-plane).
// Agg grid: plane = blockIdx&3 -> plane p runs on XCDs {p, p+4} (round-robin
// dispatch), so each XCD's gather working set is one 3.2 MB plane (L2-fits).
// Wave = 8 nodes x 8 lanes (no cross-lane reduction at all).

// ---------------------------------------------------------------- utilities
static __device__ __forceinline__ float lrelu(float x) {
  return x > 0.f ? x : 0.1f * x;
}
static __device__ __forceinline__ unsigned short f2bf(float f) {
  unsigned int u = __float_as_uint(f);
  u += 0x7FFFu + ((u >> 16) & 1u);
  return (unsigned short)(u >> 16);
}
static __device__ __forceinline__ float bf2f(unsigned short h) {
  return __uint_as_float((unsigned int)h << 16);
}

// ---------------------------------------------------------------- prep (fused):
// blocks 0..127: row i of W = W1@W2 (fp32) split hi/lo into MFMA frag order.
// block 128:     c1 = b1^T @ W2.
// blocks 129+:   p1a — per-chunk bucket histogram + pack pairs.
__global__ __launch_bounds__(256) void prep_kernel(
    const float* __restrict__ W1, const float* __restrict__ W2,
    const float* __restrict__ b1, unsigned short* __restrict__ wfrag,
    float* __restrict__ c1, const void* __restrict__ ei, int E,
    int* __restrict__ M, unsigned int* __restrict__ pairs, int NBUCK,
    int NCHUNK) {
  __shared__ int h[256];
  __shared__ int any32;
  int tid = threadIdx.x;
  if (blockIdx.x < 129) {
    if (tid >= 128) return;
    int j = tid;
    if (blockIdx.x < 128) {
      int i = blockIdx.x;
      float acc = 0.f;
      for (int k = 0; k < 128; ++k)
        acc = fmaf(W1[i * 128 + k], W2[k * 128 + j], acc);
      unsigned short hh = f2bf(acc);
      unsigned short ll = f2bf(acc - bf2f(hh));
      int fid = (((i >> 5) * 8) + (j >> 4)) * 64 + ((i >> 3) & 3) * 16 + (j & 15);
      int pos = fid * 8 + (i & 7);
      wfrag[pos] = hh;
      wfrag[16384 + pos] = ll;
    } else {
      float acc = 0.f;
      for (int k = 0; k < 128; ++k) acc = fmaf(b1[k], W2[k * 128 + j], acc);
      c1[j] = acc;
    }
    return;
  }
  int blk = blockIdx.x - 129;
  if (tid == 0) any32 = 0;
  h[tid] = 0;
  __syncthreads();
  int base = blk * CHUNK;
  int end = min(base + CHUNK, E);
  {
    const unsigned int* u = (const unsigned int*)ei;
    long long i = (long long)base + tid * 8;
    if (i < end && u[2 * i + 1] != 0u) any32 = 1;
  }
  __syncthreads();
  int is64 = !any32;
  if (is64) {
    const long long* p = (const long long*)ei;
    for (int i = base + tid; i < end; i += 256) {
      int src = (int)p[i];
      int c = (int)p[(size_t)E + i];
      atomicAdd(&h[c >> 8], 1);
      pairs[i] = ((unsigned)src << 16) | (unsigned)c;
    }
  } else {
    const int* p = (const int*)ei;
    for (int i = base + tid; i < end; i += 256) {
      int src = p[i];
      int c = p[(size_t)E + i];
      atomicAdd(&h[c >> 8], 1);
      pairs[i] = ((unsigned)src << 16) | (unsigned)c;
    }
  }
  __syncthreads();
  if (tid < NBUCK) M[tid * NCHUNK + blk] = h[tid];
}

// ---------------------------------------------------------------- matscanA:
// one block per bucket: exclusive scan of that bucket's chunk row (2/thread).
__global__ __launch_bounds__(256) void matscanA_kernel(int* __restrict__ M,
                                                       int* __restrict__ btot,
                                                       int NCHUNK) {
  __shared__ int s[256];
  int tid = threadIdx.x;
  int base = blockIdx.x * NCHUNK;
  int i0 = tid * 2, i1 = tid * 2 + 1;
  int v0 = (i0 < NCHUNK) ? M[base + i0] : 0;
  int v1 = (i1 < NCHUNK) ? M[base + i1] : 0;
  int loc = v0 + v1;
  s[tid] = loc;
  __syncthreads();
  for (int d = 1; d < 256; d <<= 1) {
    int add = (tid >= d) ? s[tid - d] : 0;
    __syncthreads();
    s[tid] += add;
    __syncthreads();
  }
  int excl = s[tid] - loc;
  if (i0 < NCHUNK) M[base + i0] = excl;
  if (i1 < NCHUNK) M[base + i1] = excl + v0;
  if (tid == 255) btot[blockIdx.x] = s[255];
}

// ---------------------------------------------------------------- pass 1c:
// scatter pairs into exact per-(chunk,bucket) staging slots.
__global__ __launch_bounds__(256) void p1c_kernel(
    const unsigned int* __restrict__ pairs, int E, const int* __restrict__ M,
    const int* __restrict__ btot, int NBUCK, int NCHUNK,
    unsigned int* __restrict__ staging) {
  __shared__ int bs[256];
  __shared__ int rowM[256];
  __shared__ int lcur[256];
  int tid = threadIdx.x;
  int blk = blockIdx.x;
  int v = (tid < NBUCK) ? btot[tid] : 0;
  bs[tid] = v;
  __syncthreads();
  for (int d = 1; d < 256; d <<= 1) {
    int add = (tid >= d) ? bs[tid - d] : 0;
    __syncthreads();
    bs[tid] += add;
    __syncthreads();
  }
  if (tid < NBUCK) rowM[tid] = M[tid * NCHUNK + blk] + (bs[tid] - v);
  lcur[tid] = 0;
  __syncthreads();
  int base = blk * CHUNK;
  int end = min(base + CHUNK, E);
  for (int i = base + tid; i < end; i += 256) {
    unsigned pv = pairs[i];
    int b = (int)((pv & 0xFFFFu) >> 8);
    int r = atomicAdd(&lcur[b], 1);
    staging[rowM[b] + r] = pv;
  }
}

// ---------------------------------------------------------------- pass 2:
// one block per bucket: emit offcnt/dis densely, scatter srcs (ushort).
__global__ __launch_bounds__(256) void p2_kernel(
    const unsigned int* __restrict__ staging, const int* __restrict__ btot,
    int NBUCK, int2* __restrict__ offcnt, float* __restrict__ dis,
    unsigned short* __restrict__ srcs, int n) {
  __shared__ int bs[256], h[256], ex[256], lcur[256];
  __shared__ unsigned int lst[LSTCAP];
  int tid = threadIdx.x;
  int b = blockIdx.x;
  int v = (tid < NBUCK) ? btot[tid] : 0;
  bs[tid] = v;
  h[tid] = 0;
  lcur[tid] = 0;
  __syncthreads();
  for (int d = 1; d < 256; d <<= 1) {
    int add = (tid >= d) ? bs[tid - d] : 0;
    __syncthreads();
    bs[tid] += add;
    __syncthreads();
  }
  int lenb = btot[b];
  int base = bs[b] - lenb;  // exclusive prefix at b
  __syncthreads();
  for (int i = tid; i < lenb; i += 256) {
    unsigned int pv = staging[base + i];
    if (i < LSTCAP) lst[i] = pv;
    atomicAdd(&h[pv & 255u], 1);
  }
  __syncthreads();
  int my = h[tid];
  ex[tid] = my;
  __syncthreads();
  for (int d = 1; d < 256; d <<= 1) {
    int add = (tid >= d) ? ex[tid - d] : 0;
    __syncthreads();
    ex[tid] += add;
    __syncthreads();
  }
  int excl = ex[tid] - my;
  ex[tid] = excl;
  int node = (b << 8) + tid;
  if (node < n) {
    offcnt[node] = make_int2(base + excl, my);
    dis[node] = rsqrtf((float)(my + 1));  // deg incl self loop >= 1
  }
  __syncthreads();
  for (int i = tid; i < lenb; i += 256) {
    unsigned int pv = (i < LSTCAP) ? lst[i] : staging[base + i];
    int ci = (int)(pv & 255u);
    int r = atomicAdd(&lcur[ci], 1);
    srcs[base + ex[ci] + r] = (unsigned short)(pv >> 16);
  }
}

// ---------------------------------------------------------------- GEMM + rsum (fused)
// blocks < gGemm: U_planes = dis[row] * (A_f32 @ W), plane-blocked bf16.
// blocks >= gGemm: r[t] = dis[t]*(dis[t] + sum_N dis[s]).
__global__ __launch_bounds__(256, 6) void gemmrs_kernel(
    const float* __restrict__ A, const unsigned short* __restrict__ wfrag,
    const float* __restrict__ dis, unsigned short* __restrict__ G, int n,
    const int2* __restrict__ offcnt, const unsigned short* __restrict__ srcs,
    float* __restrict__ r, int gGemm) {
  __shared__ unsigned short Ah[2][4][64][8];
  __shared__ unsigned short Al[2][4][64][8];
  __shared__ unsigned short Cs[32 * 136];
  __shared__ float disS[32];
  int tid = threadIdx.x;

  if (blockIdx.x >= gGemm) {  // rsum
    int t = (blockIdx.x - gGemm) * 256 + tid;
    if (t < n) {
      int2 oc = offcnt[t];
      float dt = dis[t];
      float acc = dt;  // self
      for (int i = 0; i < oc.y; ++i) acc += dis[(int)srcs[oc.x + i]];
      r[t] = dt * acc;
    }
    return;
  }

  int row0 = blockIdx.x * 32;
  if (tid < 32) {
    int gr = row0 + tid;
    disS[tid] = (gr < n) ? dis[gr] : 0.f;
  }

  const float4* A4 = (const float4*)A;
#pragma unroll
  for (int it = 0; it < 4; ++it) {
    int fi = it * 256 + tid;
    int row = fi >> 5;          // 0..31
    int c4 = fi & 31;           // float4 index along k
    int gr = row0 + row;
    float4 v = make_float4(0.f, 0.f, 0.f, 0.f);
    if (gr < n) v = A4[(size_t)gr * 32 + c4];
    unsigned short h0 = f2bf(v.x), h1 = f2bf(v.y), h2 = f2bf(v.z), h3 = f2bf(v.w);
    unsigned short l0 = f2bf(v.x - bf2f(h0)), l1 = f2bf(v.y - bf2f(h1));
    unsigned short l2 = f2bf(v.z - bf2f(h2)), l3 = f2bf(v.w - bf2f(h3));
    int band = row >> 4;
    int kslab = c4 >> 3;
    int lane = ((c4 >> 1) & 3) * 16 + (row & 15);
    int e0 = (c4 & 1) * 4;
    *(uint2*)&Ah[band][kslab][lane][e0] =
        make_uint2((unsigned int)h0 | ((unsigned int)h1 << 16),
                   (unsigned int)h2 | ((unsigned int)h3 << 16));
    *(uint2*)&Al[band][kslab][lane][e0] =
        make_uint2((unsigned int)l0 | ((unsigned int)l1 << 16),
                   (unsigned int)l2 | ((unsigned int)l3 << 16));
  }
  __syncthreads();

  int w = tid >> 6, lane = tid & 63;
  int band = w & 1, ch = w >> 1;

  f32x4 acc[4];
#pragma unroll
  for (int t = 0; t < 4; ++t) acc[t] = (f32x4){0.f, 0.f, 0.f, 0.f};

#pragma unroll
  for (int ks = 0; ks < 4; ++ks) {
    bf16x8 ahi = *(const bf16x8*)&Ah[band][ks][lane][0];
    bf16x8 alo = *(const bf16x8*)&Al[band][ks][lane][0];
#pragma unroll
    for (int ct = 0; ct < 4; ++ct) {
      size_t fb = ((size_t)(ks * 8 + ch * 4 + ct) * 64 + lane) * 8;
      bf16x8 whi = *(const bf16x8*)&wfrag[fb];
      bf16x8 wlo = *(const bf16x8*)&wfrag[16384 + fb];
      acc[ct] = __builtin_amdgcn_mfma_f32_16x16x32_bf16(ahi, whi, acc[ct], 0, 0, 0);
      acc[ct] = __builtin_amdgcn_mfma_f32_16x16x32_bf16(ahi, wlo, acc[ct], 0, 0, 0);
      acc[ct] = __builtin_amdgcn_mfma_f32_16x16x32_bf16(alo, whi, acc[ct], 0, 0, 0);
    }
  }

#pragma unroll
  for (int ct = 0; ct < 4; ++ct) {
    int col = ch * 64 + ct * 16 + (lane & 15);
#pragma unroll
    for (int rr = 0; rr < 4; ++rr) {
      int lrow = band * 16 + ((lane >> 4) << 2) + rr;
      Cs[lrow * 136 + col] = f2bf(acc[ct][rr] * disS[lrow]);
    }
  }
  __syncthreads();
  // store plane-blocked: [plane=q>>2][row][32], uint4 chunk q&3
#pragma unroll
  for (int it = 0; it < 2; ++it) {
    int fi = it * 256 + tid;   // 0..511 = 32 rows x 16 uint4
    int row = fi >> 4, q = fi & 15;
    int gr = row0 + row;
    int pl = q >> 2, qq = q & 3;
    if (gr < n)
      ((uint4*)(G + ((size_t)pl * n + gr) * 32))[qq] =
          *(uint4*)&Cs[row * 136 + q * 8];
  }
}

// ---------------------------------------------------------------- aggregation (plane-blocked, XCD-affine, no-shuffle)
// plane = blockIdx&3; wave = 8 nodes x 8 lanes; lane sl owns cols sl*4..+3
// (uint2). Group accumulates its node's whole edge list in-register.
// OUT==0: v = bf16(dis^2 * acc)   (plane-blocked)
// OUT==1: out = lrelu(dis*acc + r*c1 + b2)   (f32 row-major)
template <int OUT>
__global__ __launch_bounds__(512) void aggp_kernel(
    const unsigned short* __restrict__ g, const unsigned short* __restrict__ srcs,
    const int2* __restrict__ offcnt, const float* __restrict__ dis,
    const float* __restrict__ r, const float* __restrict__ c1,
    const float* __restrict__ b2, void* __restrict__ outv, int n) {
  int pl = blockIdx.x & 3;
  int nb = blockIdx.x >> 2;
  int wv = threadIdx.x >> 6;
  int lane = threadIdx.x & 63;
  int grp = lane >> 3;   // 0..7: node within wave
  int sl = lane & 7;     // 0..7: cols sl*4..sl*4+3
  int wid = (nb * 8 + wv) * 8 + grp;
  if (wid >= n) return;
  const unsigned short* up = g + (size_t)pl * n * 32;

  float a0, a1, a2, a3;
  {  // self term
    uint2 sv = ((const uint2*)(up + (size_t)wid * 32))[sl];
    a0 = __uint_as_float(sv.x << 16);
    a1 = __uint_as_float(sv.x & 0xFFFF0000u);
    a2 = __uint_as_float(sv.y << 16);
    a3 = __uint_as_float(sv.y & 0xFFFF0000u);
  }

#define ACC_U2(U)                                \
  do {                                           \
    a0 += __uint_as_float((U).x << 16);          \
    a1 += __uint_as_float((U).x & 0xFFFF0000u);  \
    a2 += __uint_as_float((U).y << 16);          \
    a3 += __uint_as_float((U).y & 0xFFFF0000u);  \
  } while (0)

  int2 oc = offcnt[wid];
  const unsigned short* sp = srcs + oc.x;
  int cnt = oc.y;
  int j = 0;
  for (; j + 4 <= cnt; j += 4) {
    int s0 = (int)sp[j], s1 = (int)sp[j + 1];
    int s2 = (int)sp[j + 2], s3 = (int)sp[j + 3];
    uint2 u0 = ((const uint2*)(up + (size_t)s0 * 32))[sl];
    uint2 u1 = ((const uint2*)(up + (size_t)s1 * 32))[sl];
    uint2 u2 = ((const uint2*)(up + (size_t)s2 * 32))[sl];
    uint2 u3 = ((const uint2*)(up + (size_t)s3 * 32))[sl];
    ACC_U2(u0);
    ACC_U2(u1);
    ACC_U2(u2);
    ACC_U2(u3);
  }
  if (j + 2 <= cnt) {
    int s0 = (int)sp[j], s1 = (int)sp[j + 1];
    uint2 u0 = ((const uint2*)(up + (size_t)s0 * 32))[sl];
    uint2 u1 = ((const uint2*)(up + (size_t)s1 * 32))[sl];
    ACC_U2(u0);
    ACC_U2(u1);
    j += 2;
  }
  if (j < cnt) {
    int s0 = (int)sp[j];
    uint2 u0 = ((const uint2*)(up + (size_t)s0 * 32))[sl];
    ACC_U2(u0);
  }
#undef ACC_U2

  if (OUT == 0) {
    float dw = dis[wid];
    float sc = dw * dw;
    uint2 p;
    p.x = (unsigned)f2bf(a0 * sc) | ((unsigned)f2bf(a1 * sc) << 16);
    p.y = (unsigned)f2bf(a2 * sc) | ((unsigned)f2bf(a3 * sc) << 16);
    ((uint2*)((unsigned short*)outv + ((size_t)pl * n + wid) * 32))[sl] = p;
  } else {
    float dw = dis[wid];
    float rv = r[wid];
    float4 cc = *(const float4*)&c1[pl * 32 + sl * 4];
    float4 bb = *(const float4*)&b2[pl * 32 + sl * 4];
    float4 o;
    o.x = lrelu(fmaf(a0, dw, fmaf(rv, cc.x, bb.x)));
    o.y = lrelu(fmaf(a1, dw, fmaf(rv, cc.y, bb.y)));
    o.z = lrelu(fmaf(a2, dw, fmaf(rv, cc.z, bb.z)));
    o.w = lrelu(fmaf(a3, dw, fmaf(rv, cc.w, bb.w)));
    *(float4*)((float*)outv + (size_t)wid * DF + pl * 32 + sl * 4) = o;
  }
}

// ---------------------------------------------------------------- launch
extern "C" void kernel_launch(void* const* d_in, const int* in_sizes, int n_in,
                              void* d_out, int out_size, void* d_ws, size_t ws_size,
                              hipStream_t stream) {
  const float* x  = (const float*)d_in[0];
  const void*  ei = d_in[1];
  const float* W1 = (const float*)d_in[2];
  const float* b1 = (const float*)d_in[3];
  const float* W2 = (const float*)d_in[4];
  const float* b2 = (const float*)d_in[5];
  float* out = (float*)d_out;

  int n = in_sizes[0] / DF;  // 50000
  int E = in_sizes[1] / 2;   // 800000
  int NBUCK = (n + 255) >> 8;              // 196
  int NCHUNK = (E + CHUNK - 1) / CHUNK;    // 391

  // workspace carve (16B aligned)
  char* w = (char*)d_ws;
  auto carve = [&](size_t bytes) {
    char* p = w;
    w += (bytes + 15) & ~(size_t)15;
    return p;
  };
  float* dis    = (float*)carve((size_t)n * 4);
  float* rr     = (float*)carve((size_t)n * 4);
  int2*  offcnt = (int2*)carve((size_t)n * 8);
  int*   btot   = (int*)carve((size_t)NBUCK * 4);
  int*   M      = (int*)carve((size_t)NBUCK * NCHUNK * 4);
  unsigned short* wfrag = (unsigned short*)carve(65536);   // hi+lo of W1W2
  float* c1     = (float*)carve(512);
  unsigned int* pairs   = (unsigned int*)carve((size_t)E * 4);
  unsigned int* staging = (unsigned int*)carve((size_t)E * 4);
  unsigned short* srcs  = (unsigned short*)carve((size_t)E * 2);
  unsigned short* bufU  = (unsigned short*)carve((size_t)n * DF * 2);
  unsigned short* bufV  = (unsigned short*)carve((size_t)n * DF * 2);

  // prep: W=W1@W2 frag split + c1 + p1a counting-sort pass 1
  prep_kernel<<<129 + NCHUNK, 256, 0, stream>>>(W1, W2, b1, wfrag, c1, ei, E,
                                                M, pairs, NBUCK, NCHUNK);
  matscanA_kernel<<<NBUCK, 256, 0, stream>>>(M, btot, NCHUNK);
  p1c_kernel<<<NCHUNK, 256, 0, stream>>>(pairs, E, M, btot, NBUCK, NCHUNK,
                                         staging);
  p2_kernel<<<NBUCK, 256, 0, stream>>>(staging, btot, NBUCK, offcnt, dis,
                                       srcs, n);

  int gGemm = (n + 31) / 32;        // 1563
  int gRsum = (n + 255) / 256;      // 196
  // u = dis*(x@W) plane-blocked bf16; r = rowsum(S)
  gemmrs_kernel<<<gGemm + gRsum, 256, 0, stream>>>(x, wfrag, dis, bufU, n,
                                                   offcnt, srcs, rr, gGemm);

  int gAgg = 4 * ((n + 63) / 64);   // 4 planes x 782 node-blocks = 3128
  // v = bf16(dis^2 * (sum_N+ u)), plane-blocked
  aggp_kernel<0><<<gAgg, 512, 0, stream>>>(bufU, srcs, offcnt, dis, rr, c1, b2,
                                           bufV, n);
  // out = lrelu(dis * (sum_N+ v) + r*c1 + b2), f32 row-major
  aggp_kernel<1><<<gAgg, 512, 0, stream>>>(bufV, srcs, offcnt, dis, rr, c1, b2,
                                           out, n);
}